// Round 1
// baseline (106.847 us; speedup 1.0000x reference)
//
#include <hip/hip_runtime.h>
#include <hip/hip_bf16.h>
#include <stdint.h>

#define D_DIM 2048
#define B_DIM 4096
#define BMT 128                       // output tile M = N
#define BKT 64                        // K step
#define NSPLIT 8
#define KCHUNK (B_DIM / NSPLIT)       // 512
#define NTILE (D_DIM / BMT)           // 16
#define NPAIR ((NTILE * (NTILE + 1)) / 2)  // 136 upper-triangle tile pairs

typedef __attribute__((ext_vector_type(8))) short bf16x8;
typedef __attribute__((ext_vector_type(4))) float f32x4;

__device__ __forceinline__ void gload16(const void* g, void* lds) {
    __builtin_amdgcn_global_load_lds((__attribute__((address_space(1))) void*)g,
                                     (__attribute__((address_space(3))) void*)lds,
                                     16, 0, 0);
}

__device__ __forceinline__ unsigned short f2bf(float f) {
    __hip_bfloat16 h = __float2bfloat16(f);
    return *reinterpret_cast<unsigned short*>(&h);
}

// X (B_DIM x D_DIM, f32, row-major) -> XT (D_DIM x B_DIM, bf16, row-major), XT[i][k] = X[k][i]
__global__ __launch_bounds__(256) void transpose_bf16_kernel(
    const float* __restrict__ X, unsigned short* __restrict__ XT,
    float* gsum, int* gcnt)
{
    __shared__ float tile[64][65];
    const int tid = threadIdx.x;
    const int i0 = blockIdx.x * 64;   // column block of X = row block of XT
    const int k0 = blockIdx.y * 64;   // row block of X
    if (blockIdx.x == 0 && blockIdx.y == 0 && tid == 0) { *gsum = 0.f; *gcnt = 0; }

    const int ic = tid & 63;
    const int r4 = tid >> 6;
    #pragma unroll
    for (int p = 0; p < 16; ++p) {
        const int kr = p * 4 + r4;
        tile[kr][ic] = X[(size_t)(k0 + kr) * D_DIM + i0 + ic];
    }
    __syncthreads();

    const int ir16 = tid >> 4;        // 0..15
    const int kq   = tid & 15;        // 0..15
    #pragma unroll
    for (int pi = 0; pi < 4; ++pi) {
        const int ir = pi * 16 + ir16;
        const int kc = kq * 4;
        ushort4 v;
        v.x = f2bf(tile[kc + 0][ir]);
        v.y = f2bf(tile[kc + 1][ir]);
        v.z = f2bf(tile[kc + 2][ir]);
        v.w = f2bf(tile[kc + 3][ir]);
        *reinterpret_cast<ushort4*>(XT + (size_t)(i0 + ir) * B_DIM + k0 + kc) = v;
    }
}

// C = XT_panel_i · XT_panel_j^T (Gram), fused mask + reduce.
// Tile 128x128, BK=64, 4 waves (2x2 of 64x64), mfma_f32_16x16x32_bf16.
__global__ __launch_bounds__(256) void gram_masked_kernel(
    const unsigned short* __restrict__ XT,
    const float* __restrict__ ddi,
    float* __restrict__ gsum, int* __restrict__ gcnt)
{
    __shared__ unsigned short lsA[BMT * BKT];   // [row 128][k 64] bf16, 16 KiB
    __shared__ unsigned short lsB[BMT * BKT];
    __shared__ float redf[4];
    __shared__ int   redi[4];

    const int tid  = threadIdx.x;
    const int lane = tid & 63;
    const int w    = tid >> 6;        // wave 0..3
    const int wr   = w >> 1, wc = w & 1;
    const int m16  = lane & 15;
    const int g    = lane >> 4;       // k-group 0..3

    const int pair  = blockIdx.x >> 3;       // NSPLIT=8
    const int split = blockIdx.x & 7;
    int ti = 0, rem = pair;
    while (rem >= NTILE - ti) { rem -= NTILE - ti; ++ti; }
    const int tj = ti + rem;
    const int i0 = ti * BMT, j0 = tj * BMT;
    const int kbase = split * KCHUNK;

    f32x4 acc[4][4];
    #pragma unroll
    for (int a = 0; a < 4; ++a)
        #pragma unroll
        for (int b = 0; b < 4; ++b)
            acc[a][b] = (f32x4){0.f, 0.f, 0.f, 0.f};

    // Staging: chunk = p*256 + tid; 16B chunks, row = chunk/8, within-row 16B idx = chunk%8.
    // Linear LDS dest (global_load_lds requirement) + inverse-swizzled global source:
    // linear slot (row,c8) receives global chunk (row, c8 ^ (row&7)).
    size_t gaoff[4], gboff[4];
    #pragma unroll
    for (int p = 0; p < 4; ++p) {
        const int chunk = p * 256 + tid;
        const int row = chunk >> 3;
        const int sc8 = (chunk & 7) ^ (row & 7);
        gaoff[p] = (size_t)(i0 + row) * B_DIM + kbase + sc8 * 8;
        gboff[p] = (size_t)(j0 + row) * B_DIM + kbase + sc8 * 8;
    }
    char* lbaseA = (char*)lsA + (size_t)w * 1024;   // wave-uniform segment base
    char* lbaseB = (char*)lsB + (size_t)w * 1024;

    for (int kt = 0; kt < KCHUNK / BKT; ++kt) {
        const int koff = kt * BKT;
        #pragma unroll
        for (int p = 0; p < 4; ++p) {
            gload16(XT + gaoff[p] + koff, lbaseA + p * 4096);
            gload16(XT + gboff[p] + koff, lbaseB + p * 4096);
        }
        __syncthreads();   // drains vmcnt before barrier (compiler-enforced)
        #pragma unroll
        for (int kk = 0; kk < 2; ++kk) {
            bf16x8 aF[4], bF[4];
            #pragma unroll
            for (int f = 0; f < 4; ++f) {
                const int rowA = wr * 64 + f * 16 + m16;
                const int cA = (kk * 4 + g) ^ (rowA & 7);   // swizzled read
                aF[f] = *reinterpret_cast<const bf16x8*>((const char*)lsA + rowA * 128 + cA * 16);
                const int rowB = wc * 64 + f * 16 + m16;
                const int cB = (kk * 4 + g) ^ (rowB & 7);
                bF[f] = *reinterpret_cast<const bf16x8*>((const char*)lsB + rowB * 128 + cB * 16);
            }
            #pragma unroll
            for (int fi = 0; fi < 4; ++fi)
                #pragma unroll
                for (int fj = 0; fj < 4; ++fj)
                    acc[fi][fj] = __builtin_amdgcn_mfma_f32_16x16x32_bf16(
                        aF[fi], bF[fj], acc[fi][fj], 0, 0, 0);
        }
        __syncthreads();
    }

    // Fused epilogue: masked sum + edge count.
    // C/D layout: col = lane&15, row = (lane>>4)*4 + reg  [m89/m91 verified]
    float lsum = 0.f;
    int lcnt = 0;
    #pragma unroll
    for (int fi = 0; fi < 4; ++fi) {
        const int ib = i0 + wr * 64 + fi * 16 + g * 4;
        #pragma unroll
        for (int fj = 0; fj < 4; ++fj) {
            const int j = j0 + wc * 64 + fj * 16 + m16;
            #pragma unroll
            for (int r = 0; r < 4; ++r) {
                const int i = ib + r;
                if (i < j) {
                    const float e1 = ddi[(size_t)i * D_DIM + j];
                    const float e2 = ddi[(size_t)j * D_DIM + i];
                    if (e1 > 0.f || e2 > 0.f) { lsum += acc[fi][fj][r]; ++lcnt; }
                }
            }
        }
    }
    #pragma unroll
    for (int off = 32; off > 0; off >>= 1) {
        lsum += __shfl_down(lsum, off, 64);
        lcnt += __shfl_down(lcnt, off, 64);
    }
    if (lane == 0) { redf[w] = lsum; redi[w] = lcnt; }
    __syncthreads();
    if (tid == 0) {
        atomicAdd(gsum, redf[0] + redf[1] + redf[2] + redf[3]);
        if (split == 0)
            atomicAdd(gcnt, redi[0] + redi[1] + redi[2] + redi[3]);
    }
}

__global__ void finalize_kernel(const float* gsum, const int* gcnt, float* out) {
    out[0] = gsum[0] / ((float)B_DIM * fmaxf((float)gcnt[0], 1.0f));
}

extern "C" void kernel_launch(void* const* d_in, const int* in_sizes, int n_in,
                              void* d_out, int out_size, void* d_ws, size_t ws_size,
                              hipStream_t stream) {
    const float* X   = (const float*)d_in[0];   // drug_probs (B_DIM x D_DIM)
    const float* ddi = (const float*)d_in[1];   // ddi_matrix (D_DIM x D_DIM)
    float* out = (float*)d_out;

    const size_t XT_BYTES = (size_t)D_DIM * B_DIM * sizeof(unsigned short);  // 16 MiB
    if (ws_size < XT_BYTES + 16) return;  // scratch too small (not expected)

    unsigned short* XT = (unsigned short*)d_ws;
    float* gsum = (float*)((char*)d_ws + XT_BYTES);
    int*   gcnt = (int*)((char*)d_ws + XT_BYTES + sizeof(float));

    transpose_bf16_kernel<<<dim3(D_DIM / 64, B_DIM / 64), 256, 0, stream>>>(X, XT, gsum, gcnt);
    gram_masked_kernel<<<NPAIR * NSPLIT, 256, 0, stream>>>(XT, ddi, gsum, gcnt);
    finalize_kernel<<<1, 1, 0, stream>>>(gsum, gcnt, out);
}

// Round 2
// 61.254 us; speedup vs baseline: 1.7443x; 1.7443x over previous
//
#include <hip/hip_runtime.h>
#include <hip/hip_bf16.h>
#include <stdint.h>

#define D_DIM 2048
#define B_DIM 4096
#define BMT 128                       // output tile M = N
#define BKT 64                        // K step
#define NSPLIT 8
#define KCHUNK (B_DIM / NSPLIT)       // 512
#define NKT (KCHUNK / BKT)            // 8
#define NTILE (D_DIM / BMT)           // 16
#define NPAIR ((NTILE * (NTILE + 1)) / 2)  // 136 upper-triangle tile pairs
#define MWORDS (D_DIM / 64)           // 32 mask words per row

typedef __attribute__((ext_vector_type(8))) short bf16x8;
typedef __attribute__((ext_vector_type(4))) float f32x4;

__device__ __forceinline__ void gload16(const void* g, void* lds) {
    __builtin_amdgcn_global_load_lds((__attribute__((address_space(1))) void*)g,
                                     (__attribute__((address_space(3))) void*)lds,
                                     16, 0, 0);
}

__device__ __forceinline__ unsigned short f2bf(float f) {
    __hip_bfloat16 h = __float2bfloat16(f);
    return *reinterpret_cast<unsigned short*>(&h);
}

// X (B_DIM x D_DIM, f32, row-major) -> XT (D_DIM x B_DIM, bf16, row-major), XT[i][k] = X[k][i]
// Also zero-inits gsum/gcnt (block (0,0)), safely ordered before mask/gram dispatches.
__global__ __launch_bounds__(256) void transpose_bf16_kernel(
    const float* __restrict__ X, unsigned short* __restrict__ XT,
    float* gsum, int* gcnt)
{
    __shared__ float tile[64][65];
    const int tid = threadIdx.x;
    const int i0 = blockIdx.x * 64;   // column block of X = row block of XT
    const int k0 = blockIdx.y * 64;   // row block of X
    if (blockIdx.x == 0 && blockIdx.y == 0 && tid == 0) { *gsum = 0.f; *gcnt = 0; }

    const int ic = tid & 63;
    const int r4 = tid >> 6;
    #pragma unroll
    for (int p = 0; p < 16; ++p) {
        const int kr = p * 4 + r4;
        tile[kr][ic] = X[(size_t)(k0 + kr) * D_DIM + i0 + ic];
    }
    __syncthreads();

    const int ir16 = tid >> 4;        // 0..15
    const int kq   = tid & 15;        // 0..15
    #pragma unroll
    for (int pi = 0; pi < 4; ++pi) {
        const int ir = pi * 16 + ir16;
        const int kc = kq * 4;
        ushort4 v;
        v.x = f2bf(tile[kc + 0][ir]);
        v.y = f2bf(tile[kc + 1][ir]);
        v.z = f2bf(tile[kc + 2][ir]);
        v.w = f2bf(tile[kc + 3][ir]);
        *reinterpret_cast<ushort4*>(XT + (size_t)(i0 + ir) * B_DIM + k0 + kc) = v;
    }
}

// Build packed upper-triangle mask: bit (i,j) = (i<j) && (ddi[i][j]>0 || ddi[j][i]>0).
// mask64[i][jw] covers j in [jw*64, jw*64+64). Also accumulates total edge count.
__global__ __launch_bounds__(256) void mask_kernel(
    const float* __restrict__ ddi,
    unsigned long long* __restrict__ mask64,
    int* __restrict__ gcnt)
{
    __shared__ float tileT[64][65];   // ddi[c0+k][r0+i], transposed access
    const int tid = threadIdx.x;
    const int r0 = blockIdx.x * 64;
    const int c0 = blockIdx.y * 64;

    // load tile (c0..c0+63, r0..r0+63) coalesced
    const int ic = tid & 63;
    const int r4 = tid >> 6;
    #pragma unroll
    for (int p = 0; p < 16; ++p) {
        const int kr = p * 4 + r4;
        tileT[kr][ic] = ddi[(size_t)(c0 + kr) * D_DIM + r0 + ic];
    }
    __syncthreads();

    const int lane = tid & 63;
    const int w    = tid >> 6;
    int cnt = 0;
    #pragma unroll
    for (int rr = 0; rr < 16; ++rr) {
        const int li = w * 16 + rr;
        const int gi = r0 + li;
        const int gj = c0 + lane;
        const float a  = ddi[(size_t)gi * D_DIM + c0 + lane];  // coalesced row read
        const float at = tileT[lane][li];                      // ddi[gj][gi], stride-65 no conflict
        const bool bit = (gi < gj) && (a > 0.f || at > 0.f);
        const unsigned long long word = __ballot(bit);
        if (lane == 0) mask64[(size_t)gi * MWORDS + blockIdx.y] = word;
        cnt += bit ? 1 : 0;
    }
    // block reduce count
    #pragma unroll
    for (int off = 32; off > 0; off >>= 1) cnt += __shfl_down(cnt, off, 64);
    __shared__ int redi[4];
    if (lane == 0) redi[w] = cnt;
    __syncthreads();
    if (tid == 0) atomicAdd(gcnt, redi[0] + redi[1] + redi[2] + redi[3]);
}

// C = XT_panel_i · XT_panel_j^T (Gram), fused bitmask + reduce.
// Tile 128x128, BK=64, 4 waves (2x2 of 64x64), mfma_f32_16x16x32_bf16,
// double-buffered LDS with 2-phase prefetch schedule (T3 minimum).
__global__ __launch_bounds__(256) void gram_masked_kernel(
    const unsigned short* __restrict__ XT,
    const unsigned long long* __restrict__ mask64,
    float* __restrict__ gsum)
{
    __shared__ unsigned short lsA[2][BMT * BKT];   // 2 x 16 KiB
    __shared__ unsigned short lsB[2][BMT * BKT];
    __shared__ float redf[4];

    const int tid  = threadIdx.x;
    const int lane = tid & 63;
    const int w    = tid >> 6;        // wave 0..3
    const int wr   = w >> 1, wc = w & 1;
    const int m16  = lane & 15;
    const int g    = lane >> 4;       // k-group 0..3

    const int pair  = blockIdx.x >> 3;       // NSPLIT=8; split = bid&7 -> XCD = split,
    const int split = blockIdx.x & 7;        // so each XCD sees one disjoint 2 MiB K-chunk of XT
    int ti = 0, rem = pair;
    while (rem >= NTILE - ti) { rem -= NTILE - ti; ++ti; }
    const int tj = ti + rem;
    const int i0 = ti * BMT, j0 = tj * BMT;
    const int kbase = split * KCHUNK;

    f32x4 acc[4][4];
    #pragma unroll
    for (int a = 0; a < 4; ++a)
        #pragma unroll
        for (int b = 0; b < 4; ++b)
            acc[a][b] = (f32x4){0.f, 0.f, 0.f, 0.f};

    // Staging: chunk = p*256 + tid; 16B chunks, row = chunk/8, within-row 16B idx = chunk%8.
    // Linear LDS dest (global_load_lds requirement) + inverse-swizzled global source:
    // linear slot (row,c8) receives global chunk (row, c8 ^ (row&7)).  [rule #21]
    size_t gaoff[4], gboff[4];
    #pragma unroll
    for (int p = 0; p < 4; ++p) {
        const int chunk = p * 256 + tid;
        const int row = chunk >> 3;
        const int sc8 = (chunk & 7) ^ (row & 7);
        gaoff[p] = (size_t)(i0 + row) * B_DIM + kbase + sc8 * 8;
        gboff[p] = (size_t)(j0 + row) * B_DIM + kbase + sc8 * 8;
    }

    auto stage = [&](int buf, int koff) {
        char* bA = (char*)lsA[buf] + (size_t)w * 1024;   // wave-uniform segment base
        char* bB = (char*)lsB[buf] + (size_t)w * 1024;
        #pragma unroll
        for (int p = 0; p < 4; ++p) {
            gload16(XT + gaoff[p] + koff, bA + p * 4096);
            gload16(XT + gboff[p] + koff, bB + p * 4096);
        }
    };

    stage(0, 0);
    __syncthreads();                 // buf0 ready
    int cur = 0;
    for (int kt = 0; kt < NKT; ++kt) {
        if (kt + 1 < NKT) stage(cur ^ 1, (kt + 1) * BKT);   // async prefetch, overlaps compute
        #pragma unroll
        for (int kk = 0; kk < 2; ++kk) {
            bf16x8 aF[4], bF[4];
            #pragma unroll
            for (int f = 0; f < 4; ++f) {
                const int rowA = wr * 64 + f * 16 + m16;
                const int cA = (kk * 4 + g) ^ (rowA & 7);   // swizzled read
                aF[f] = *reinterpret_cast<const bf16x8*>((const char*)lsA[cur] + rowA * 128 + cA * 16);
                const int rowB = wc * 64 + f * 16 + m16;
                const int cB = (kk * 4 + g) ^ (rowB & 7);
                bF[f] = *reinterpret_cast<const bf16x8*>((const char*)lsB[cur] + rowB * 128 + cB * 16);
            }
            #pragma unroll
            for (int fi = 0; fi < 4; ++fi)
                #pragma unroll
                for (int fj = 0; fj < 4; ++fj)
                    acc[fi][fj] = __builtin_amdgcn_mfma_f32_16x16x32_bf16(
                        aF[fi], bF[fj], acc[fi][fj], 0, 0, 0);
        }
        if (kt + 1 < NKT) {
            __syncthreads();         // drains prefetch vmcnt + guards buffer reuse
            cur ^= 1;
        }
    }

    // Fused epilogue: masked sum from packed bits (mask encodes i<j already).
    // C/D layout: col = lane&15, row = (lane>>4)*4 + reg  [m89/m91 verified]
    float lsum = 0.f;
    const int jb = (j0 + wc * 64) >> 6;   // single mask word column per lane
    #pragma unroll
    for (int fi = 0; fi < 4; ++fi) {
        #pragma unroll
        for (int r = 0; r < 4; ++r) {
            const int i = i0 + wr * 64 + fi * 16 + g * 4 + r;
            const unsigned long long wword = mask64[(size_t)i * MWORDS + jb];
            #pragma unroll
            for (int fj = 0; fj < 4; ++fj) {
                if ((wword >> (fj * 16 + m16)) & 1ull) lsum += acc[fi][fj][r];
            }
        }
    }
    #pragma unroll
    for (int off = 32; off > 0; off >>= 1) lsum += __shfl_down(lsum, off, 64);
    if (lane == 0) redf[w] = lsum;
    __syncthreads();
    if (tid == 0) atomicAdd(gsum, redf[0] + redf[1] + redf[2] + redf[3]);
}

__global__ void finalize_kernel(const float* gsum, const int* gcnt, float* out) {
    out[0] = gsum[0] / ((float)B_DIM * fmaxf((float)gcnt[0], 1.0f));
}

extern "C" void kernel_launch(void* const* d_in, const int* in_sizes, int n_in,
                              void* d_out, int out_size, void* d_ws, size_t ws_size,
                              hipStream_t stream) {
    const float* X   = (const float*)d_in[0];   // drug_probs (B_DIM x D_DIM)
    const float* ddi = (const float*)d_in[1];   // ddi_matrix (D_DIM x D_DIM)
    float* out = (float*)d_out;

    const size_t XT_BYTES   = (size_t)D_DIM * B_DIM * sizeof(unsigned short);      // 16 MiB
    const size_t MASK_BYTES = (size_t)D_DIM * MWORDS * sizeof(unsigned long long); // 512 KiB
    if (ws_size < XT_BYTES + MASK_BYTES + 16) return;

    unsigned short* XT = (unsigned short*)d_ws;
    unsigned long long* mask64 = (unsigned long long*)((char*)d_ws + XT_BYTES);
    float* gsum = (float*)((char*)d_ws + XT_BYTES + MASK_BYTES);
    int*   gcnt = (int*)((char*)d_ws + XT_BYTES + MASK_BYTES + sizeof(float));

    transpose_bf16_kernel<<<dim3(D_DIM / 64, B_DIM / 64), 256, 0, stream>>>(X, XT, gsum, gcnt);
    mask_kernel<<<dim3(D_DIM / 64, D_DIM / 64), 256, 0, stream>>>(ddi, mask64, gcnt);
    gram_masked_kernel<<<NPAIR * NSPLIT, 256, 0, stream>>>(XT, mask64, gsum);
    finalize_kernel<<<1, 1, 0, stream>>>(gsum, gcnt, out);
}